// Round 4
// baseline (768.649 us; speedup 1.0000x reference)
//
#include <hip/hip_runtime.h>

// DeepKoopmanNoDec — fp32 in/out.
// R4: (1) encoder_tgt v3: C-stationary MFMA GEMM — wave owns 64x128 output
//     tile (128 VGPR acc), B-frags streamed L2->registers (read once per
//     block), h in a single in-place 65KB LDS buffer. LDS reads 9.3GB->1.7GB,
//     barriers 35->8. (2) scan v2: A column + B column in registers per lane,
//     z read via wave-uniform LDS broadcast — kills the 12.6GB LDS re-read.
// Shapes: B=2048, M=64, STATE=32, EMBED=96, LATENT=128, HIDDEN=512.

typedef unsigned short u16;
typedef __attribute__((ext_vector_type(8))) short bf16x8;   // MFMA A/B frag (4 VGPRs)
typedef __attribute__((ext_vector_type(4))) float f32x4;    // MFMA C/D frag

// ws layout: bf16 B-frag weights, then fp32 z_k
#define OFF_W1 0              // 32 frags   (K=32 , N=512)
#define OFF_W2 16384          // 512 frags  (K=512, N=512)
#define OFF_W3 278528         // 512 frags
#define OFF_WO 540672         // 96 frags   (K=512, N=96)
#define OFF_ZK_BYTES 1179648  // fp32 z_k: 2048*128 floats

// d_out regions (float elements): z_pred | x_pred | z_target
#define XPRED_OFF 16777216
#define ZTGT_OFF  20971520

__device__ __forceinline__ float bf2f(u16 u) {
  unsigned int i = ((unsigned int)u) << 16;
  return __builtin_bit_cast(float, i);
}
__device__ __forceinline__ u16 f2bf(float f) {   // round-to-nearest-even
  unsigned int i = __builtin_bit_cast(unsigned int, f);
  i = (i + 0x7FFFu + ((i >> 16) & 1u)) >> 16;
  return (u16)i;
}

// ---------------------------------------------------------------------------
// Prep: swizzle fp32 weights (row-major K x N) into bf16 B-fragment-linear
// layout. frag f = ct*(K/32)+ks; lane l holds W[ks*32+(l>>4)*8+j][ct*16+(l&15)]
// at u16 offset f*512 + l*8 -> one coalesced dwordx4 per lane in the GEMM.
// ---------------------------------------------------------------------------
__global__ void prep_swizzle(const float* __restrict__ W1, const float* __restrict__ W2,
                             const float* __restrict__ W3, const float* __restrict__ Wo,
                             u16* __restrict__ dst) {
  int f = blockIdx.x;
  int l = threadIdx.x;
  const float* src; int K, N; u16* d;
  if (f < 32)        { src = W1; K = 32;  N = 512; d = dst + OFF_W1; }
  else if (f < 544)  { src = W2; K = 512; N = 512; d = dst + OFF_W2; f -= 32; }
  else if (f < 1056) { src = W3; K = 512; N = 512; d = dst + OFF_W3; f -= 544; }
  else               { src = Wo; K = 512; N = 96;  d = dst + OFF_WO; f -= 1056; }
  const int KF = K >> 5;
  const int ct = f / KF, ks = f - ct * KF;
  const int q = l >> 4, n = l & 15;
  const int kbase = ks * 32 + q * 8;
  const int col = ct * 16 + n;
  bf16x8 vh;
  #pragma unroll
  for (int j = 0; j < 8; ++j)
    vh[j] = (short)f2bf(src[(size_t)(kbase + j) * N + col]);
  *(bf16x8*)(d + ((size_t)f * 64 + l) * 8) = vh;
}

// ---------------------------------------------------------------------------
// encoder_tgt v3. Block = 64 rows, 4 waves. Wave wv owns cols
// [wv*128, wv*128+128) (8 ct) x all 64 rows (4 rt): acc[4][8] f32x4.
// h: single LDS buffer, row-major bf16, stride HS=520 u16 (1040 B, 16-aligned
// for b128; conflict-benign). Updated in place: k-loop fully reads h, barrier,
// transform writes, barrier.
// ---------------------------------------------------------------------------
#define HS 520

__device__ __forceinline__ void xform_store(u16* __restrict__ hbuf,
                                            f32x4 (&acc)[4][8],
                                            const float* __restrict__ bias,
                                            int wv, int q, int n) {
  #pragma unroll
  for (int ct = 0; ct < 8; ++ct) {
    const int col = wv * 128 + ct * 16 + n;
    const float bi = bias[col];
    #pragma unroll
    for (int rt = 0; rt < 4; ++rt) {
      #pragma unroll
      for (int rr = 0; rr < 4; ++rr) {
        const int row = rt * 16 + q * 4 + rr;
        hbuf[row * HS + col] = f2bf(fmaxf(acc[rt][ct][rr] + bi, 0.f));
      }
    }
  }
}

__global__ __launch_bounds__(256, 2) void encoder_tgt(
    const float* __restrict__ xnext, const u16* __restrict__ wf,
    const float* __restrict__ b1, const float* __restrict__ b2,
    const float* __restrict__ b3, const float* __restrict__ bo_,
    float* __restrict__ ztgt) {
  __shared__ __align__(16) u16 hbuf[64 * HS];   // 66,560 B
  const int tid = threadIdx.x;
  const int wv = tid >> 6, l = tid & 63;
  const int q = l >> 4, n = l & 15;
  const size_t row0 = (size_t)blockIdx.x * 64;

  // ---- layer 1 (K=32): A = x frags; also fp32 x pass-through for rt==wv ----
  {
    f32x4 acc[4][8];
    #pragma unroll
    for (int rt = 0; rt < 4; ++rt)
      #pragma unroll
      for (int ct = 0; ct < 8; ++ct)
        acc[rt][ct] = (f32x4){0.f, 0.f, 0.f, 0.f};
    bf16x8 ax[4];
    #pragma unroll
    for (int rt = 0; rt < 4; ++rt) {
      const float* xs = xnext + (row0 + rt * 16 + n) * 32 + q * 8;
      f32x4 x0 = *(const f32x4*)(xs);
      f32x4 x1 = *(const f32x4*)(xs + 4);
      #pragma unroll
      for (int j = 0; j < 4; ++j) { ax[rt][j] = (short)f2bf(x0[j]); ax[rt][4 + j] = (short)f2bf(x1[j]); }
      if (rt == wv) {   // exact fp32 pass-through (wave-uniform branch)
        *(f32x4*)(ztgt + (row0 + rt * 16 + n) * 128 + q * 8)     = x0;
        *(f32x4*)(ztgt + (row0 + rt * 16 + n) * 128 + q * 8 + 4) = x1;
      }
    }
    #pragma unroll
    for (int ct = 0; ct < 8; ++ct) {
      bf16x8 bb = *(const bf16x8*)(wf + OFF_W1 + ((size_t)(wv * 8 + ct) * 64 + l) * 8);
      #pragma unroll
      for (int rt = 0; rt < 4; ++rt)
        acc[rt][ct] = __builtin_amdgcn_mfma_f32_16x16x32_bf16(ax[rt], bb, acc[rt][ct], 0, 0, 0);
    }
    xform_store(hbuf, acc, b1, wv, q, n);
  }
  __syncthreads();

  // ---- layers 2 & 3 (K=512, N=512) ----
  for (int lyr = 0; lyr < 2; ++lyr) {
    const u16* w = wf + (lyr ? OFF_W3 : OFF_W2);
    const float* bias = lyr ? b3 : b2;
    f32x4 acc[4][8];
    #pragma unroll
    for (int rt = 0; rt < 4; ++rt)
      #pragma unroll
      for (int ct = 0; ct < 8; ++ct)
        acc[rt][ct] = (f32x4){0.f, 0.f, 0.f, 0.f};
    bf16x8 bb[8];
    #pragma unroll
    for (int ct = 0; ct < 8; ++ct)
      bb[ct] = *(const bf16x8*)(w + (((size_t)(wv * 8 + ct) * 16) * 64 + l) * 8);
    #pragma unroll
    for (int kc = 0; kc < 16; ++kc) {
      bf16x8 bn[8];
      if (kc < 15) {
        #pragma unroll
        for (int ct = 0; ct < 8; ++ct)
          bn[ct] = *(const bf16x8*)(w + (((size_t)(wv * 8 + ct) * 16 + kc + 1) * 64 + l) * 8);
      }
      bf16x8 aA[4];
      #pragma unroll
      for (int rt = 0; rt < 4; ++rt)
        aA[rt] = *(const bf16x8*)(hbuf + (rt * 16 + n) * HS + kc * 32 + q * 8);
      #pragma unroll
      for (int rt = 0; rt < 4; ++rt)
        #pragma unroll
        for (int ct = 0; ct < 8; ++ct)
          acc[rt][ct] = __builtin_amdgcn_mfma_f32_16x16x32_bf16(aA[rt], bb[ct], acc[rt][ct], 0, 0, 0);
      if (kc < 15) {
        #pragma unroll
        for (int ct = 0; ct < 8; ++ct) bb[ct] = bn[ct];
      }
    }
    __syncthreads();                 // all h reads complete
    xform_store(hbuf, acc, bias, wv, q, n);
    __syncthreads();                 // h rewritten, visible
  }

  // ---- output layer (K=512, N=96): waves 0..2 take 2 ct each ----
  if (wv < 3) {
    const u16* wo = wf + OFF_WO;
    f32x4 acc[4][2];
    #pragma unroll
    for (int rt = 0; rt < 4; ++rt)
      #pragma unroll
      for (int cc = 0; cc < 2; ++cc)
        acc[rt][cc] = (f32x4){0.f, 0.f, 0.f, 0.f};
    #pragma unroll
    for (int kc = 0; kc < 16; ++kc) {
      bf16x8 bw[2];
      #pragma unroll
      for (int cc = 0; cc < 2; ++cc)
        bw[cc] = *(const bf16x8*)(wo + (((size_t)(wv * 2 + cc) * 16 + kc) * 64 + l) * 8);
      bf16x8 aA[4];
      #pragma unroll
      for (int rt = 0; rt < 4; ++rt)
        aA[rt] = *(const bf16x8*)(hbuf + (rt * 16 + n) * HS + kc * 32 + q * 8);
      #pragma unroll
      for (int rt = 0; rt < 4; ++rt)
        #pragma unroll
        for (int cc = 0; cc < 2; ++cc)
          acc[rt][cc] = __builtin_amdgcn_mfma_f32_16x16x32_bf16(aA[rt], bw[cc], acc[rt][cc], 0, 0, 0);
    }
    #pragma unroll
    for (int cc = 0; cc < 2; ++cc) {
      const int ctg = wv * 2 + cc;
      const float bi = bo_[ctg * 16 + n];
      #pragma unroll
      for (int rt = 0; rt < 4; ++rt)
        #pragma unroll
        for (int rr = 0; rr < 4; ++rr)
          ztgt[(row0 + rt * 16 + q * 4 + rr) * 128 + 32 + ctg * 16 + n] = acc[rt][cc][rr] + bi;
    }
  }
}

// ---------------------------------------------------------------------------
// z_k encoder — exact fp32 VALU (2048 rows). Unchanged from R3.
// ---------------------------------------------------------------------------
__global__ __launch_bounds__(256) void encoder_zk_f32(
    const float* __restrict__ xk,
    const float* __restrict__ W1, const float* __restrict__ b1,
    const float* __restrict__ W2, const float* __restrict__ b2,
    const float* __restrict__ W3, const float* __restrict__ b3,
    const float* __restrict__ Wo, const float* __restrict__ bo_,
    float* __restrict__ zk_out) {
  __shared__ __align__(16) float hb[2][8][512];
  __shared__ __align__(16) float xb[8][32];
  const int t = threadIdx.x;
  const int row0 = blockIdx.x * 8;
  {
    int r = t >> 5, j = t & 31;
    float v = xk[(size_t)(row0 + r) * 32 + j];
    xb[r][j] = v;
    zk_out[(size_t)(row0 + r) * 128 + j] = v;
  }
  __syncthreads();
  const int c0 = t, c1 = t + 256;
  {
    float a0[8], a1[8];
    const float i0 = b1[c0], i1 = b1[c1];
    #pragma unroll
    for (int r = 0; r < 8; ++r) { a0[r] = i0; a1[r] = i1; }
    for (int k = 0; k < 32; k += 4) {
      float w00 = W1[(size_t)(k+0)*512 + c0], w10 = W1[(size_t)(k+0)*512 + c1];
      float w01 = W1[(size_t)(k+1)*512 + c0], w11 = W1[(size_t)(k+1)*512 + c1];
      float w02 = W1[(size_t)(k+2)*512 + c0], w12 = W1[(size_t)(k+2)*512 + c1];
      float w03 = W1[(size_t)(k+3)*512 + c0], w13 = W1[(size_t)(k+3)*512 + c1];
      #pragma unroll
      for (int r = 0; r < 8; ++r) {
        f32x4 z = *(const f32x4*)&xb[r][k];
        a0[r] += z[0]*w00 + z[1]*w01 + z[2]*w02 + z[3]*w03;
        a1[r] += z[0]*w10 + z[1]*w11 + z[2]*w12 + z[3]*w13;
      }
    }
    #pragma unroll
    for (int r = 0; r < 8; ++r) { hb[0][r][c0] = fmaxf(a0[r], 0.f); hb[0][r][c1] = fmaxf(a1[r], 0.f); }
  }
  __syncthreads();
  #pragma unroll
  for (int lyr = 0; lyr < 2; ++lyr) {
    const float* W = lyr ? W3 : W2;
    const float* bb = lyr ? b3 : b2;
    const float (*hin)[512] = hb[lyr & 1];
    float (*hout)[512] = hb[(lyr & 1) ^ 1];
    float a0[8], a1[8];
    const float i0 = bb[c0], i1 = bb[c1];
    #pragma unroll
    for (int r = 0; r < 8; ++r) { a0[r] = i0; a1[r] = i1; }
    for (int k = 0; k < 512; k += 4) {
      float w00 = W[(size_t)(k+0)*512 + c0], w10 = W[(size_t)(k+0)*512 + c1];
      float w01 = W[(size_t)(k+1)*512 + c0], w11 = W[(size_t)(k+1)*512 + c1];
      float w02 = W[(size_t)(k+2)*512 + c0], w12 = W[(size_t)(k+2)*512 + c1];
      float w03 = W[(size_t)(k+3)*512 + c0], w13 = W[(size_t)(k+3)*512 + c1];
      #pragma unroll
      for (int r = 0; r < 8; ++r) {
        f32x4 z = *(const f32x4*)&hin[r][k];
        a0[r] += z[0]*w00 + z[1]*w01 + z[2]*w02 + z[3]*w03;
        a1[r] += z[0]*w10 + z[1]*w11 + z[2]*w12 + z[3]*w13;
      }
    }
    #pragma unroll
    for (int r = 0; r < 8; ++r) { hout[r][c0] = fmaxf(a0[r], 0.f); hout[r][c1] = fmaxf(a1[r], 0.f); }
    __syncthreads();
  }
  if (t < 96) {
    float a[8];
    const float i0 = bo_[t];
    #pragma unroll
    for (int r = 0; r < 8; ++r) a[r] = i0;
    for (int k = 0; k < 512; k += 4) {
      float w0 = Wo[(size_t)(k+0)*96 + t];
      float w1 = Wo[(size_t)(k+1)*96 + t];
      float w2 = Wo[(size_t)(k+2)*96 + t];
      float w3 = Wo[(size_t)(k+3)*96 + t];
      #pragma unroll
      for (int r = 0; r < 8; ++r) {
        f32x4 z = *(const f32x4*)&hb[0][r][k];
        a[r] += z[0]*w0 + z[1]*w1 + z[2]*w2 + z[3]*w3;
      }
    }
    #pragma unroll
    for (int r = 0; r < 8; ++r)
      zk_out[(size_t)(row0 + r) * 128 + 32 + t] = a[r];
  }
}

// ---------------------------------------------------------------------------
// scan v2: lane owns latent col c; A[:,c] (128) + Bmat[:,c] (8) in VGPRs.
// z broadcast from LDS (wave-uniform addresses -> same-address broadcast,
// conflict-free). Block = 2 batch rows x 128 cols = 4 waves; 1024 blocks.
// Per-step LDS traffic ~3 KB/block (was 384 KB).
// ---------------------------------------------------------------------------
__global__ __launch_bounds__(256) void scan_kernel(
    const float* __restrict__ zk, const float* __restrict__ Af,
    const float* __restrict__ Bm, const float* __restrict__ useq,
    float* __restrict__ zpred, float* __restrict__ xpred) {
  __shared__ __align__(16) float ub[2][512];      // u for 2 rows: [r][s*8+j]
  __shared__ __align__(16) float zb[2][2][128];   // ping-pong x 2 rows
  const int t = threadIdx.x;
  const int b0 = blockIdx.x * 2;
  const int wv = t >> 6, l = t & 63;
  const int r = wv >> 1;
  const int c = (wv & 1) * 64 + l;

  float a[128];
  #pragma unroll
  for (int k = 0; k < 128; ++k) a[k] = Af[(size_t)k * 128 + c];
  float bc[8];
  #pragma unroll
  for (int j = 0; j < 8; ++j) bc[j] = Bm[(size_t)j * 128 + c];

  for (int i = t; i < 1024; i += 256) ub[i >> 9][i & 511] = useq[(size_t)b0 * 512 + i];
  for (int i = t; i < 256; i += 256) zb[0][i >> 7][i & 127] = zk[(size_t)b0 * 128 + i];
  __syncthreads();

  const size_t o = (size_t)(b0 + r) * 64;
  int cur = 0;
  for (int s = 0; s < 64; ++s) {
    const float* uu = &ub[r][s * 8];
    const float* zz = &zb[cur][r][0];
    float acc0 = 0.f, acc1 = 0.f, acc2 = 0.f, acc3 = 0.f;
    f32x4 u0 = *(const f32x4*)(uu);
    f32x4 u1 = *(const f32x4*)(uu + 4);
    #pragma unroll
    for (int j = 0; j < 4; ++j) { acc0 += u0[j] * bc[j]; acc1 += u1[j] * bc[4 + j]; }
    #pragma unroll
    for (int k = 0; k < 128; k += 4) {
      f32x4 z4 = *(const f32x4*)(zz + k);       // uniform addr -> broadcast
      acc0 += z4[0] * a[k];
      acc1 += z4[1] * a[k + 1];
      acc2 += z4[2] * a[k + 2];
      acc3 += z4[3] * a[k + 3];
    }
    const float z = (acc0 + acc2) + (acc1 + acc3);
    zb[cur ^ 1][r][c] = z;
    zpred[(o + s) * 128 + c] = z;
    if (c < 32) xpred[(o + s) * 32 + c] = z;
    __syncthreads();
    cur ^= 1;
  }
}

// ---------------------------------------------------------------------------
extern "C" void kernel_launch(void* const* d_in, const int* in_sizes, int n_in,
                              void* d_out, int out_size, void* d_ws, size_t ws_size,
                              hipStream_t stream) {
  (void)in_sizes; (void)n_in; (void)out_size; (void)ws_size;
  const float* xk    = (const float*)d_in[0];
  const float* useq  = (const float*)d_in[1];
  const float* xnext = (const float*)d_in[2];
  const float* W1 = (const float*)d_in[3];
  const float* b1 = (const float*)d_in[4];
  const float* W2 = (const float*)d_in[5];
  const float* b2 = (const float*)d_in[6];
  const float* W3 = (const float*)d_in[7];
  const float* b3 = (const float*)d_in[8];
  const float* Wo = (const float*)d_in[9];
  const float* bo = (const float*)d_in[10];
  const float* A  = (const float*)d_in[11];
  const float* Bm = (const float*)d_in[12];

  float* out   = (float*)d_out;
  float* zpred = out;
  float* xpred = out + XPRED_OFF;
  float* ztgt  = out + ZTGT_OFF;
  u16*   wf    = (u16*)d_ws;
  float* zkw   = (float*)((char*)d_ws + OFF_ZK_BYTES);

  prep_swizzle<<<1152, 64, 0, stream>>>(W1, W2, W3, Wo, wf);
  encoder_zk_f32<<<256, 256, 0, stream>>>(xk, W1, b1, W2, b2, W3, b3, Wo, bo, zkw);
  scan_kernel<<<1024, 256, 0, stream>>>(zkw, A, Bm, useq, zpred, xpred);
  encoder_tgt<<<2048, 256, 0, stream>>>(xnext, wf, b1, b2, b3, bo, ztgt);
}